// Round 2
// baseline (524.404 us; speedup 1.0000x reference)
//
#include <hip/hip_runtime.h>
#include <cmath>

#define C_ 64
#define H_ 192
#define W_ 640
#define BATCH 4
#define OUTC 74
#define DISP 10
#define WT 64

constexpr long SLICE = (long)C_ * H_ * W_;   // 7,864,320 elems per (image,batch)
constexpr int RED_BLOCKS = 512;              // blocks per slice in stats pass
constexpr long N4 = SLICE / 4;               // 1,966,080 float4 per slice

// ---------------- Kernel 1: per-(image,batch) sum & sumsq ----------------
__global__ __launch_bounds__(256)
void stats_kernel(const float* __restrict__ left, const float* __restrict__ right,
                  double* __restrict__ acc)
{
    int bid = blockIdx.x;
    int slice = bid / RED_BLOCKS;              // 0..3 left b, 4..7 right b
    int blk = bid - slice * RED_BLOCKS;
    const float* src = ((slice < BATCH) ? left : right) + (long)(slice & 3) * SLICE;
    const float4* src4 = (const float4*)src;

    double s = 0.0, s2 = 0.0;
    for (long i = (long)blk * 256 + threadIdx.x; i < N4; i += (long)RED_BLOCKS * 256) {
        float4 v = src4[i];
        s  += ((double)v.x + (double)v.y) + ((double)v.z + (double)v.w);
        s2 += ((double)v.x * v.x + (double)v.y * v.y)
            + ((double)v.z * v.z + (double)v.w * v.w);
    }
#pragma unroll
    for (int off = 32; off; off >>= 1) {
        s  += __shfl_down(s, off);
        s2 += __shfl_down(s2, off);
    }
    __shared__ double sh[8];
    int lane = threadIdx.x & 63, wid = threadIdx.x >> 6;
    if (lane == 0) { sh[wid] = s; sh[4 + wid] = s2; }
    __syncthreads();
    if (threadIdx.x == 0) {
        double ts  = sh[0] + sh[1] + sh[2] + sh[3];
        double ts2 = sh[4] + sh[5] + sh[6] + sh[7];
        atomicAdd(&acc[slice * 2], ts);
        atomicAdd(&acc[slice * 2 + 1], ts2);
    }
}

// ---------------- Kernel 2: finalize mean / rstd ----------------
__global__ void finalize_kernel(const double* __restrict__ acc, float* __restrict__ stats)
{
    int t = threadIdx.x;
    if (t < 8) {
        double S = acc[t * 2], S2 = acc[t * 2 + 1];
        double N = (double)SLICE;
        double mean = S / N;
        double var = (S2 - S * S / N) / (N - 1.0);   // ddof=1 (torch-style unbiased)
        if (var < 0.0) var = 0.0;
        double sd = sqrt(var);
        stats[t]     = (float)mean;                   // mean: [0..3]=left, [4..7]=right
        stats[8 + t] = (float)(1.0 / (sd + 1e-5));    // rstd: [8..11]=left, [12..15]=right
    }
}

// ---------------- Kernel 3: fused LN + PE + cost volume + conv + concat ----------------
__global__ __launch_bounds__(256)
void main_kernel(const float* __restrict__ left, const float* __restrict__ right,
                 const float* __restrict__ homo, const float* __restrict__ lnw,
                 const float* __restrict__ lnb, const float* __restrict__ gpw,
                 const float* __restrict__ gpb, const float* __restrict__ stats,
                 float* __restrict__ out)
{
    int bid = blockIdx.x;
    int wblk = bid % (W_ / WT);
    int h = (bid / (W_ / WT)) % H_;
    int b = bid / ((W_ / WT) * H_);
    int w0 = wblk * WT;
    int tid = threadIdx.x;

    __shared__ float l_s[C_][WT + 1];        // LN+PE'd left, stride 65 (2-way max)
    __shared__ float r_s[C_][WT + 10 + 1];   // LN+PE'd right w/ circular halo, stride 75
    __shared__ float freq_s[16];
    __shared__ float gpw_s[80];
    __shared__ float lnw_s[C_], lnb_s[C_];

    // inv_freq[j] = 200^(-j/16) = 2^(-j * log2(200)/16)
    if (tid < 16) freq_s[tid] = exp2f(-(float)tid * 0.47774101186092114f);
    if (tid < 80) gpw_s[tid] = gpw[tid];
    if (tid < C_) { lnw_s[tid] = lnw[tid]; lnb_s[tid] = lnb[tid]; }

    float h00 = homo[b * 9 + 0], h01 = homo[b * 9 + 1], h02 = homo[b * 9 + 2];
    float h10 = homo[b * 9 + 3], h11 = homo[b * 9 + 4], h12 = homo[b * 9 + 5];
    float mean_l = stats[b],     rstd_l = stats[8 + b];
    float mean_r = stats[4 + b], rstd_r = stats[12 + b];
    float px = (float)(h - H_ / 2);

    __syncthreads();   // freq_s / lnw_s / lnb_s ready

    long in_base  = ((long)b * C_   * H_ + h) * W_;   // + c*H*W
    long out_base = ((long)b * OUTC * H_ + h) * W_;

    // ---- stage left: LN + PE, and copy raw input to out[:, 0:64] ----
    for (int idx = tid; idx < C_ * WT; idx += 256) {
        int c = idx >> 6, w = idx & 63;
        int gw = w0 + w;
        float raw = left[in_base + (long)c * H_ * W_ + gw];
        out[out_base + (long)c * H_ * W_ + gw] = raw;   // concat channel 0..63 = raw input
        float v = (raw - mean_l) * rstd_l * lnw_s[c] + lnb_s[c];
        int k = c >> 1, j = k >> 1;
        float base = (c & 1) ? (float)(gw - W_ / 2) : px;
        float arg = base * freq_s[j];
        float pe = (k & 1) ? cosf(arg) : sinf(arg);
        l_s[c][w] = v + pe;
    }

    // ---- stage right: LN + homography PE, columns (w0-10 .. w0+63) mod W ----
    for (int idx = tid; idx < C_ * (WT + 10); idx += 256) {
        int c = idx / (WT + 10), wsi = idx - c * (WT + 10);
        int gw = w0 - 10 + wsi;
        if (gw < 0) gw += W_;
        float raw = right[in_base + (long)c * H_ * W_ + gw];
        float v = (raw - mean_r) * rstd_r * lnw_s[c] + lnb_s[c];
        float py = (float)(gw - W_ / 2);
        float rot = (c & 1) ? (h10 * px + h11 * py + h12)
                            : (h00 * px + h01 * py + h02);
        int k = c >> 1, j = k >> 1;
        float arg = rot * freq_s[j];
        float pe = (k & 1) ? cosf(arg) : sinf(arg);
        r_s[c][wsi] = v + pe;
    }
    __syncthreads();

    // ---- cost volume + grouped 1x1 conv: 4 lanes per pixel, 16 channels each ----
    int pix = tid >> 2, q = tid & 3;
    float wgt[2][10];
#pragma unroll
    for (int d = 0; d < DISP; ++d) {
        wgt[0][d] = gpw_s[d * 8 + 2 * q];
        wgt[1][d] = gpw_s[d * 8 + 2 * q + 1];
    }
    float acc[10] = {0, 0, 0, 0, 0, 0, 0, 0, 0, 0};
    int c0 = q * 16;
#pragma unroll
    for (int i = 0; i < 16; ++i) {
        int c = c0 + i;
        float lv = l_s[c][pix];
        const float* rrow = &r_s[c][pix];   // src col for disp d is (w - d - 1) mod W -> rrow[9-d]
#pragma unroll
        for (int d = 0; d < DISP; ++d)
            acc[d] = fmaf(lv * rrow[9 - d], wgt[i >> 3][d], acc[d]);
    }
#pragma unroll
    for (int d = 0; d < DISP; ++d) {
        acc[d] += __shfl_xor(acc[d], 1);
        acc[d] += __shfl_xor(acc[d], 2);
    }
#pragma unroll
    for (int m = 0; m < 3; ++m) {
        int d = q + 4 * m;
        if (d < DISP)
            out[out_base + (long)(C_ + d) * H_ * W_ + w0 + pix] = acc[d] + gpb[d];
    }
}

extern "C" void kernel_launch(void* const* d_in, const int* in_sizes, int n_in,
                              void* d_out, int out_size, void* d_ws, size_t ws_size,
                              hipStream_t stream)
{
    const float* left  = (const float*)d_in[0];
    const float* right = (const float*)d_in[1];
    const float* homo  = (const float*)d_in[2];
    const float* lnw   = (const float*)d_in[3];
    const float* lnb   = (const float*)d_in[4];
    const float* gpw   = (const float*)d_in[5];
    const float* gpb   = (const float*)d_in[6];
    float* out = (float*)d_out;

    double* acc  = (double*)d_ws;                     // 16 doubles (zeroed below)
    float* stats = (float*)((char*)d_ws + 128);       // 16 floats

    hipMemsetAsync(d_ws, 0, 128, stream);
    stats_kernel<<<RED_BLOCKS * 8, 256, 0, stream>>>(left, right, acc);
    finalize_kernel<<<1, 64, 0, stream>>>(acc, stats);
    main_kernel<<<BATCH * H_ * (W_ / WT), 256, 0, stream>>>(
        left, right, homo, lnw, lnb, gpw, gpb, stats, out);
}

// Round 7
// 452.727 us; speedup vs baseline: 1.1583x; 1.1583x over previous
//
#include <hip/hip_runtime.h>
#include <cmath>

#define C_ 64
#define H_ 192
#define W_ 640
#define BATCH 4
#define OUTC 74
#define DISP 10
#define WT 64
#define HW_ (H_ * W_)

constexpr long SLICE = (long)C_ * H_ * W_;   // 7,864,320 elems per (image,batch)
constexpr int RED_BLOCKS = 512;              // blocks per slice in stats pass
constexpr long N4 = SLICE / 4;               // float4 count per slice

// fast sin/cos with explicit periodic reduction (avoids ocml Payne-Hanek slow path).
// |err| ~ 1e-4 worst case at |x|~1e3 — threshold is 0.18, margin is huge.
__device__ __forceinline__ float fsin(float x) {
    float k = rintf(x * 0.15915494309189535f);
    float xr = fmaf(k, -6.283185307179586f, x);
    return __sinf(xr);
}
__device__ __forceinline__ float fcos(float x) {
    float k = rintf(x * 0.15915494309189535f);
    float xr = fmaf(k, -6.283185307179586f, x);
    return __cosf(xr);
}

// ---------------- Kernel 1: per-(image,batch) sum & sumsq (f32 inner, f64 reduce) ----------------
__global__ __launch_bounds__(256)
void stats_kernel(const float* __restrict__ left, const float* __restrict__ right,
                  double* __restrict__ acc)
{
    int bid = blockIdx.x;
    int slice = bid / RED_BLOCKS;              // 0..3 left b, 4..7 right b
    int blk = bid - slice * RED_BLOCKS;
    const float* src = ((slice < BATCH) ? left : right) + (long)(slice & 3) * SLICE;
    const float4* src4 = (const float4*)src;

    float s = 0.f, s2 = 0.f;
    for (long i = (long)blk * 256 + threadIdx.x; i < N4; i += (long)RED_BLOCKS * 256) {
        float4 v = src4[i];
        s  += (v.x + v.y) + (v.z + v.w);
        s2 += fmaf(v.x, v.x, v.y * v.y) + fmaf(v.z, v.z, v.w * v.w);
    }
    double ds = (double)s, ds2 = (double)s2;
#pragma unroll
    for (int off = 32; off; off >>= 1) {
        ds  += __shfl_down(ds, off);
        ds2 += __shfl_down(ds2, off);
    }
    __shared__ double sh[8];
    int lane = threadIdx.x & 63, wid = threadIdx.x >> 6;
    if (lane == 0) { sh[wid] = ds; sh[4 + wid] = ds2; }
    __syncthreads();
    if (threadIdx.x == 0) {
        double ts  = sh[0] + sh[1] + sh[2] + sh[3];
        double ts2 = sh[4] + sh[5] + sh[6] + sh[7];
        atomicAdd(&acc[slice * 2], ts);
        atomicAdd(&acc[slice * 2 + 1], ts2);
    }
}

// ---------------- Kernel 2: finalize mean / rstd ----------------
__global__ void finalize_kernel(const double* __restrict__ acc, float* __restrict__ stats)
{
    int t = threadIdx.x;
    if (t < 8) {
        double S = acc[t * 2], S2 = acc[t * 2 + 1];
        double N = (double)SLICE;
        double mean = S / N;
        double var = (S2 - S * S / N) / (N - 1.0);   // ddof=1 (unbiased)
        if (var < 0.0) var = 0.0;
        double sd = sqrt(var);
        stats[t]     = (float)mean;                   // mean: [0..3]=left, [4..7]=right
        stats[8 + t] = (float)(1.0 / (sd + 1e-5));    // rstd
    }
}

// ---------------- Kernel 3: fused LN + PE + cost volume + conv + concat ----------------
__global__ __launch_bounds__(256)
void main_kernel(const float* __restrict__ left, const float* __restrict__ right,
                 const float* __restrict__ homo, const float* __restrict__ lnw,
                 const float* __restrict__ lnb, const float* __restrict__ gpw,
                 const float* __restrict__ gpb, const float* __restrict__ stats,
                 float* __restrict__ out)
{
    int bid = blockIdx.x;
    int wblk = bid % (W_ / WT);
    int h = (bid / (W_ / WT)) % H_;
    int b = bid / ((W_ / WT) * H_);
    int w0 = wblk * WT;
    int tid = threadIdx.x;

    __shared__ float l_s[C_][WT + 1];        // LN+PE'd left, stride 65 (2-way max)
    __shared__ float r_s[C_][WT + 10 + 1];   // LN+PE'd right w/ circular halo, stride 75
    __shared__ float freq_s[16];
    __shared__ float gpw_s[80];
    __shared__ float lnw_s[C_], lnb_s[C_];

    // inv_freq[j] = 200^(-j/16) = 2^(-j * log2(200)/16)
    if (tid < 16) freq_s[tid] = exp2f(-(float)tid * 0.47774101186092114f);
    if (tid < 80) gpw_s[tid] = gpw[tid];
    if (tid < C_) { lnw_s[tid] = lnw[tid]; lnb_s[tid] = lnb[tid]; }

    float h00 = homo[b * 9 + 0], h01 = homo[b * 9 + 1], h02 = homo[b * 9 + 2];
    float h10 = homo[b * 9 + 3], h11 = homo[b * 9 + 4], h12 = homo[b * 9 + 5];
    float mean_l = stats[b],     rstd_l = stats[8 + b];
    float mean_r = stats[4 + b], rstd_r = stats[12 + b];
    float px = (float)(h - H_ / 2);
    float rb0 = fmaf(h00, px, h02);   // rot_x = rb0 + h01*py  (even channels)
    float rb1 = fmaf(h10, px, h12);   // rot_y = rb1 + h11*py  (odd channels)

    __syncthreads();   // freq_s / lnw_s / lnb_s ready

    long in_base  = ((long)b * C_   * H_ + h) * W_;   // + c*H*W
    long out_base = ((long)b * OUTC * H_ + h) * W_;

    // ---- stage left: float4 loads, LN + PE, raw copy to out[:, 0:64] ----
    for (int idx = tid; idx < C_ * 16; idx += 256) {
        int c = idx >> 4;
        int w4 = (idx & 15) << 2;
        int gw = w0 + w4;
        float4 rv = *(const float4*)(left + in_base + (long)c * HW_ + gw);
        *(float4*)(out + out_base + (long)c * HW_ + gw) = rv;
        float r[4] = {rv.x, rv.y, rv.z, rv.w};
        float g = rstd_l * lnw_s[c];
        float bb = fmaf(-mean_l, g, lnb_s[c]);
        int kk = c >> 1, j = kk >> 1;
        float fr = freq_s[j];
        bool cc = kk & 1;
        if (c & 1) {
#pragma unroll
            for (int jj = 0; jj < 4; ++jj) {
                float arg = (float)(gw + jj - W_ / 2) * fr;
                float pe = cc ? fcos(arg) : fsin(arg);
                l_s[c][w4 + jj] = fmaf(r[jj], g, bb) + pe;
            }
        } else {
            float arg = px * fr;
            float pe = cc ? fcos(arg) : fsin(arg);
#pragma unroll
            for (int jj = 0; jj < 4; ++jj)
                l_s[c][w4 + jj] = fmaf(r[jj], g, bb) + pe;
        }
    }

    // ---- stage right body: wsi 10..73 <-> gw in [w0, w0+64), float4 ----
    for (int idx = tid; idx < C_ * 16; idx += 256) {
        int c = idx >> 4;
        int w4 = (idx & 15) << 2;
        int gw = w0 + w4;
        float4 rv = *(const float4*)(right + in_base + (long)c * HW_ + gw);
        float r[4] = {rv.x, rv.y, rv.z, rv.w};
        float g = rstd_r * lnw_s[c];
        float bb = fmaf(-mean_r, g, lnb_s[c]);
        int kk = c >> 1, j = kk >> 1;
        float fr = freq_s[j];
        bool cc = kk & 1;
        bool odd = c & 1;
        float rb = odd ? rb1 : rb0;
        float hy = odd ? h11 : h01;
#pragma unroll
        for (int jj = 0; jj < 4; ++jj) {
            float py = (float)(gw + jj - W_ / 2);
            float arg = fmaf(hy, py, rb) * fr;
            float pe = cc ? fcos(arg) : fsin(arg);
            r_s[c][10 + w4 + jj] = fmaf(r[jj], g, bb) + pe;
        }
    }

    // ---- stage right halo: wsi 0..9 <-> gw in [w0-10, w0), 3 wrapped float4 per channel ----
    for (int idx = tid; idx < C_ * 3; idx += 256) {
        int c = (idx * 683) >> 11;      // idx / 3
        int t = idx - c * 3;
        int gw4 = w0 - 12 + 4 * t;
        if (gw4 < 0) gw4 += W_;          // circular (contiguous & aligned after wrap)
        float4 rv = *(const float4*)(right + in_base + (long)c * HW_ + gw4);
        float r[4] = {rv.x, rv.y, rv.z, rv.w};
        float g = rstd_r * lnw_s[c];
        float bb = fmaf(-mean_r, g, lnb_s[c]);
        int kk = c >> 1, j = kk >> 1;
        float fr = freq_s[j];
        bool cc = kk & 1;
        bool odd = c & 1;
        float rb = odd ? rb1 : rb0;
        float hy = odd ? h11 : h01;
#pragma unroll
        for (int jj = 0; jj < 4; ++jj) {
            int wsi = 4 * t + jj - 2;
            if ((unsigned)wsi < 10u) {
                float py = (float)(gw4 + jj - W_ / 2);   // PE at true source column
                float arg = fmaf(hy, py, rb) * fr;
                float pe = cc ? fcos(arg) : fsin(arg);
                r_s[c][wsi] = fmaf(r[jj], g, bb) + pe;
            }
        }
    }
    __syncthreads();

    // ---- cost volume + grouped 1x1 conv: 4 lanes per pixel, 16 channels each ----
    int pix = tid >> 2, q = tid & 3;
    float wgt[2][10];
#pragma unroll
    for (int d = 0; d < DISP; ++d) {
        wgt[0][d] = gpw_s[d * 8 + 2 * q];
        wgt[1][d] = gpw_s[d * 8 + 2 * q + 1];
    }
    float acc[10] = {0, 0, 0, 0, 0, 0, 0, 0, 0, 0};
    int c0 = q * 16;
#pragma unroll
    for (int i = 0; i < 16; ++i) {
        int c = c0 + i;
        float lv = l_s[c][pix];
        const float* rrow = &r_s[c][pix];   // disp d reads rrow[9-d]  ((w-d-1) mod W)
#pragma unroll
        for (int d = 0; d < DISP; ++d)
            acc[d] = fmaf(lv * rrow[9 - d], wgt[i >> 3][d], acc[d]);
    }
#pragma unroll
    for (int d = 0; d < DISP; ++d) {
        acc[d] += __shfl_xor(acc[d], 1);
        acc[d] += __shfl_xor(acc[d], 2);
    }
#pragma unroll
    for (int m = 0; m < 3; ++m) {
        int d = q + 4 * m;
        if (d < DISP)
            out[out_base + (long)(C_ + d) * HW_ + w0 + pix] = acc[d] + gpb[d];
    }
}

extern "C" void kernel_launch(void* const* d_in, const int* in_sizes, int n_in,
                              void* d_out, int out_size, void* d_ws, size_t ws_size,
                              hipStream_t stream)
{
    const float* left  = (const float*)d_in[0];
    const float* right = (const float*)d_in[1];
    const float* homo  = (const float*)d_in[2];
    const float* lnw   = (const float*)d_in[3];
    const float* lnb   = (const float*)d_in[4];
    const float* gpw   = (const float*)d_in[5];
    const float* gpb   = (const float*)d_in[6];
    float* out = (float*)d_out;

    double* acc  = (double*)d_ws;                     // 16 doubles (zeroed below)
    float* stats = (float*)((char*)d_ws + 128);       // 16 floats

    hipMemsetAsync(d_ws, 0, 128, stream);
    stats_kernel<<<RED_BLOCKS * 8, 256, 0, stream>>>(left, right, acc);
    finalize_kernel<<<1, 64, 0, stream>>>(acc, stats);
    main_kernel<<<BATCH * H_ * (W_ / WT), 256, 0, stream>>>(
        left, right, homo, lnw, lnb, gpw, gpb, stats, out);
}